// Round 4
// baseline (219.670 us; speedup 1.0000x reference)
//
#include <hip/hip_runtime.h>
#include <hip/hip_bf16.h>

#define N_NODES 50000
#define N_EDGES 800000
#define N_GRAPHS 128
#define IN_CH 16
#define HIDDEN 64
#define OUT_CH 2

// ---- bucket CSR params ----
#define BSHIFT 7
#define BNODES 128
#define NB ((N_NODES + BNODES - 1) / BNODES)     // 391 buckets
#define BCAP 3072                                // per-bucket csr capacity (mean 2046, sd ~45)
#define WT1_LD 18                                // W1^T stride: 2-way banks (free)
#define AGG_LD 72                                // bf16 LDS stride for MFMA frags
#define W2T_ENT (HIDDEN * AGG_LD)                // 4608 ushorts prepped W2^T
#define EQ4 (N_EDGES / 4)                        // 200000 int4 edge quads

typedef __attribute__((ext_vector_type(8))) short bf16x8;
typedef __attribute__((ext_vector_type(4))) float f32x4;

__device__ __forceinline__ float bf2f(unsigned short u) {
    return __uint_as_float(((unsigned)u) << 16);
}
__device__ __forceinline__ unsigned short f2bf(float f) {
    __hip_bfloat16 h = __float2bfloat16(f);
    return *reinterpret_cast<unsigned short*>(&h);
}

// ---------------- P0: init (zero accumulators + degree counters, prep W2^T) ----------------

__global__ void init_kernel(int* __restrict__ cnt, float* __restrict__ sums,
                            float* __restrict__ cntg,
                            const float* __restrict__ W2, unsigned short* __restrict__ w2t) {
    int t = blockIdx.x * blockDim.x + threadIdx.x;
    int stride = gridDim.x * blockDim.x;
    for (int i = t; i < N_NODES; i += stride) cnt[i] = 0;
    for (int i = t; i < N_GRAPHS * HIDDEN; i += stride) sums[i] = 0.0f;
    for (int i = t; i < N_GRAPHS; i += stride) cntg[i] = 0.0f;
    for (int i = t; i < HIDDEN * HIDDEN; i += stride) {
        int k = i >> 6, c = i & 63;
        w2t[c * AGG_LD + k] = f2bf(W2[i]);
    }
}

// ---------------- P1: degree count (800K global atomics, no barriers) ----------------

__global__ void degree_kernel(const int* __restrict__ dst, int* __restrict__ cnt) {
    int i = blockIdx.x * blockDim.x + threadIdx.x;
    if (i >= EQ4) return;
    int4 d = ((const int4*)dst)[i];
    if ((unsigned)d.x < N_NODES) atomicAdd(&cnt[d.x], 1);
    if ((unsigned)d.y < N_NODES) atomicAdd(&cnt[d.y], 1);
    if ((unsigned)d.z < N_NODES) atomicAdd(&cnt[d.z], 1);
    if ((unsigned)d.w < N_NODES) atomicAdd(&cnt[d.w], 1);
}

// ---------------- P2: per-bucket prefix -> rowptr/cur/dinv + xs prep ----------------

__global__ void bucket_prefix_kernel(const int* __restrict__ cnt, int* __restrict__ rowptr,
                                     int* __restrict__ cur, float* __restrict__ dinv,
                                     const float* __restrict__ x, unsigned short* __restrict__ xs) {
    __shared__ int sc[BNODES];
    __shared__ float sdv[BNODES];
    int b = blockIdx.x;
    int t = threadIdx.x;
    int n = b * BNODES + t;
    int c = 0;
    if (t < BNODES) {
        c = (n < N_NODES) ? cnt[n] : 0;
        sc[t] = c;
        sdv[t] = rsqrtf((float)(c + 1));   // +1 self-loop
    }
    __syncthreads();
    for (int off = 1; off < BNODES; off <<= 1) {
        int u = (t >= off && t < BNODES) ? sc[t - off] : 0;
        __syncthreads();
        if (t < BNODES) sc[t] += u;
        __syncthreads();
    }
    if (t < BNODES && n < N_NODES) {
        int ex = sc[t] - c;
        int rp = b * BCAP + ex;
        rowptr[n] = rp;
        cur[n] = rp;
        dinv[n] = sdv[t];
    }
    __syncthreads();
    // prep x' = dinv * x (bf16) for this bucket's 128 nodes (coalesced)
    for (int i = t; i < BNODES * IN_CH; i += 256) {
        int nl = i >> 4;
        int n2 = b * BNODES + nl;
        if (n2 < N_NODES) xs[n2 * IN_CH + (i & 15)] = f2bf(sdv[nl] * x[n2 * IN_CH + (i & 15)]);
    }
}

// ---------------- P3: edge scatter into CSR (800K global atomics, no barriers) ----------------

__global__ void scatter_kernel(const int* __restrict__ src, const int* __restrict__ dst,
                               int* __restrict__ cur, int* __restrict__ csr) {
    int i = blockIdx.x * blockDim.x + threadIdx.x;
    if (i >= EQ4) return;
    int4 d = ((const int4*)dst)[i];
    int4 s = ((const int4*)src)[i];
    if ((unsigned)d.x < N_NODES) { int p = atomicAdd(&cur[d.x], 1); csr[p] = s.x; }
    if ((unsigned)d.y < N_NODES) { int p = atomicAdd(&cur[d.y], 1); csr[p] = s.y; }
    if ((unsigned)d.z < N_NODES) { int p = atomicAdd(&cur[d.z], 1); csr[p] = s.z; }
    if ((unsigned)d.w < N_NODES) { int p = atomicAdd(&cur[d.w], 1); csr[p] = s.w; }
}

// ---------------- fused layer 1: aggregate(x' bf16) -> LDS -> linear+relu -> h1' (bf16) ----------------

// 512 threads, 8 waves, 2 nodes per wave.
// Phase A: 4 lanes/edge (ushort4), 16 edge slots x 2 k = 32 slots per node.
__global__ void fused_l1_kernel(const unsigned short* __restrict__ xs, const int* __restrict__ csr_src,
                                const int* __restrict__ rowptr, const int* __restrict__ cnt,
                                const float* __restrict__ dinv, const float* __restrict__ W,
                                const float* __restrict__ b, __hip_bfloat16* __restrict__ h) {
    __shared__ float sWT[HIDDEN * WT1_LD];   // 4.6 KB
    __shared__ float sx[16 * IN_CH];         // 1 KB
    int t = threadIdx.x;
    for (int i = t; i < IN_CH * HIDDEN; i += 512) {
        int k = i >> 6, c = i & 63;
        sWT[c * WT1_LD + k] = W[i];
    }

    int n0 = blockIdx.x * 16;
    int w = t >> 6;               // 0..7
    int lane = t & 63;
    int e16 = lane >> 2;          // edge slot 0..15
    int cc = (lane & 3) * 4;      // channel quad

    int lens[2], starts[2];
#pragma unroll
    for (int q = 0; q < 2; q++) {
        int n = n0 + w * 2 + q;
        lens[q] = cnt[n];
        starts[q] = rowptr[n];
    }

    // batched index loads (4 outstanding)
    int sidxv[2][2];
    float msk[2][2];
#pragma unroll
    for (int q = 0; q < 2; q++) {
        int last = lens[q] - 1;
        int lastc = last < 0 ? 0 : last;
        int sg = lens[q] > 0 ? -1 : 0;
#pragma unroll
        for (int k = 0; k < 2; k++) {
            int j = e16 + 16 * k;
            int jj = j <= last ? j : lastc;
            msk[q][k] = (j <= last) ? 1.0f : 0.0f;
            sidxv[q][k] = csr_src[starts[q] + jj] & sg;
        }
    }
    // batched payload gathers (4 outstanding)
    ushort4 raw[2][2];
#pragma unroll
    for (int q = 0; q < 2; q++)
#pragma unroll
        for (int k = 0; k < 2; k++)
            raw[q][k] = *(const ushort4*)&xs[sidxv[q][k] * IN_CH + cc];

#pragma unroll
    for (int q = 0; q < 2; q++) {
        int row = w * 2 + q;
        int n = n0 + row;
        int len = lens[q];
        float4 acc = make_float4(0.f, 0.f, 0.f, 0.f);
#pragma unroll
        for (int k = 0; k < 2; k++) {
            float m = msk[q][k];
            acc.x += m * bf2f(raw[q][k].x);
            acc.y += m * bf2f(raw[q][k].y);
            acc.z += m * bf2f(raw[q][k].z);
            acc.w += m * bf2f(raw[q][k].w);
        }
        if (len > 32) {   // rare tail (wave-uniform branch)
            int last = len - 1;
            int start = starts[q];
            int iters = (len + 31) >> 5;
            for (int m2 = 1; m2 < iters; m2++) {
                int base2 = m2 * 32 + e16;
#pragma unroll
                for (int k = 0; k < 2; k++) {
                    int j = base2 + 16 * k;
                    int jj = j <= last ? j : last;
                    float m = j <= last ? 1.0f : 0.0f;
                    int s = csr_src[start + jj];
                    ushort4 xv = *(const ushort4*)&xs[s * IN_CH + cc];
                    acc.x += m * bf2f(xv.x);
                    acc.y += m * bf2f(xv.y);
                    acc.z += m * bf2f(xv.z);
                    acc.w += m * bf2f(xv.w);
                }
            }
        }
#pragma unroll
        for (int m = 4; m <= 32; m <<= 1) {
            acc.x += __shfl_xor(acc.x, m, 64);
            acc.y += __shfl_xor(acc.y, m, 64);
            acc.z += __shfl_xor(acc.z, m, 64);
            acc.w += __shfl_xor(acc.w, m, 64);
        }
        if (lane < 4) {
            float dn = dinv[n];
            ushort4 xsv = *(const ushort4*)&xs[n * IN_CH + cc];
            float4 v;
            v.x = dn * (acc.x + bf2f(xsv.x));
            v.y = dn * (acc.y + bf2f(xsv.y));
            v.z = dn * (acc.z + bf2f(xsv.z));
            v.w = dn * (acc.w + bf2f(xsv.w));
            *(float4*)&sx[row * IN_CH + cc] = v;
        }
    }
    __syncthreads();

    // Phase B: 16 rows over 8 waves x 2
    int c = t & 63;
    float bias = b[c];
#pragma unroll
    for (int nb = 0; nb < 2; nb++) {
        int row = nb * 8 + w;
        int n = n0 + row;
        float acch = bias;
#pragma unroll
        for (int k4 = 0; k4 < IN_CH; k4 += 4) {
            float4 a = *(const float4*)&sx[row * IN_CH + k4];
            float2 w0 = *(const float2*)&sWT[c * WT1_LD + k4];
            float2 w1 = *(const float2*)&sWT[c * WT1_LD + k4 + 2];
            acch += a.x * w0.x + a.y * w0.y + a.z * w1.x + a.w * w1.y;
        }
        float v = acch > 0.0f ? acch : 0.0f;
        h[n * HIDDEN + c] = __float2bfloat16(dinv[n] * v);   // pre-scaled h1'
    }
}

// ---------------- fused layer 2: aggregate(h1') -> MFMA gemm2 -> pool ----------------

// 512 threads, 8 waves, 2 nodes per wave.
// Phase A: 8 lanes/edge (uint4), 8 edge slots x 4 k = 32 slots per node; 8 uint4 in flight.
__global__ void fused_l2_kernel(const __hip_bfloat16* __restrict__ h, const int* __restrict__ csr_src,
                                const int* __restrict__ rowptr, const int* __restrict__ cnt,
                                const float* __restrict__ dinv, const unsigned short* __restrict__ w2t,
                                const float* __restrict__ b, const int* __restrict__ batch,
                                float* __restrict__ sums, float* __restrict__ cntg) {
    __shared__ unsigned short sW[W2T_ENT];           // 9.2 KB (prepped, flat copy)
    __shared__ unsigned short sagg[16 * AGG_LD];     // 2.3 KB
    int t = threadIdx.x;
    {   // flat uint4 copy of prepped W2^T (conflict-free b128)
        const uint4* wp = (const uint4*)w2t;
        uint4* sWv = (uint4*)sW;
#pragma unroll
        for (int i = 0; i < 2; i++) {
            int idx = i * 512 + t;
            if (idx < W2T_ENT / 8) sWv[idx] = wp[idx];
        }
    }

    int n0 = blockIdx.x * 16;
    int w = t >> 6;               // 0..7
    int lane = t & 63;
    int e8 = lane >> 3;          // edge slot 0..7
    int cc8 = (lane & 7) * 8;    // channel octet
    const unsigned short* hu = (const unsigned short*)h;

    int lens[2], starts[2];
#pragma unroll
    for (int q = 0; q < 2; q++) {
        int n = n0 + w * 2 + q;
        lens[q] = cnt[n];
        starts[q] = rowptr[n];
    }

    // batched index loads (8 outstanding)
    int sidxv[2][4];
    float msk[2][4];
#pragma unroll
    for (int q = 0; q < 2; q++) {
        int last = lens[q] - 1;
        int lastc = last < 0 ? 0 : last;
        int sg = lens[q] > 0 ? -1 : 0;
#pragma unroll
        for (int k = 0; k < 4; k++) {
            int j = e8 + 8 * k;
            int jj = j <= last ? j : lastc;
            msk[q][k] = (j <= last) ? 1.0f : 0.0f;
            sidxv[q][k] = csr_src[starts[q] + jj] & sg;
        }
    }
    // batched payload gathers (8 uint4 outstanding)
    uint4 raw[2][4];
#pragma unroll
    for (int q = 0; q < 2; q++)
#pragma unroll
        for (int k = 0; k < 4; k++)
            raw[q][k] = *(const uint4*)&hu[sidxv[q][k] * HIDDEN + cc8];

#pragma unroll
    for (int q = 0; q < 2; q++) {
        int row = w * 2 + q;
        int n = n0 + row;
        int len = lens[q];
        float4 alo = make_float4(0.f, 0.f, 0.f, 0.f);
        float4 ahi = make_float4(0.f, 0.f, 0.f, 0.f);
#pragma unroll
        for (int k = 0; k < 4; k++) {
            float m = msk[q][k];
            uint4 r = raw[q][k];
            alo.x += m * __uint_as_float(r.x << 16);
            alo.y += m * __uint_as_float(r.x & 0xffff0000u);
            alo.z += m * __uint_as_float(r.y << 16);
            alo.w += m * __uint_as_float(r.y & 0xffff0000u);
            ahi.x += m * __uint_as_float(r.z << 16);
            ahi.y += m * __uint_as_float(r.z & 0xffff0000u);
            ahi.z += m * __uint_as_float(r.w << 16);
            ahi.w += m * __uint_as_float(r.w & 0xffff0000u);
        }
        if (len > 32) {   // rare tail (wave-uniform branch)
            int last = len - 1;
            int start = starts[q];
            int iters = (len + 31) >> 5;
            for (int m2 = 1; m2 < iters; m2++) {
                int base2 = m2 * 32 + e8;
#pragma unroll
                for (int k = 0; k < 4; k++) {
                    int j = base2 + 8 * k;
                    int jj = j <= last ? j : last;
                    float m = j <= last ? 1.0f : 0.0f;
                    int s = csr_src[start + jj];
                    uint4 r = *(const uint4*)&hu[s * HIDDEN + cc8];
                    alo.x += m * __uint_as_float(r.x << 16);
                    alo.y += m * __uint_as_float(r.x & 0xffff0000u);
                    alo.z += m * __uint_as_float(r.y << 16);
                    alo.w += m * __uint_as_float(r.y & 0xffff0000u);
                    ahi.x += m * __uint_as_float(r.z << 16);
                    ahi.y += m * __uint_as_float(r.z & 0xffff0000u);
                    ahi.z += m * __uint_as_float(r.w << 16);
                    ahi.w += m * __uint_as_float(r.w & 0xffff0000u);
                }
            }
        }
#pragma unroll
        for (int m = 8; m <= 32; m <<= 1) {
            alo.x += __shfl_xor(alo.x, m, 64);
            alo.y += __shfl_xor(alo.y, m, 64);
            alo.z += __shfl_xor(alo.z, m, 64);
            alo.w += __shfl_xor(alo.w, m, 64);
            ahi.x += __shfl_xor(ahi.x, m, 64);
            ahi.y += __shfl_xor(ahi.y, m, 64);
            ahi.z += __shfl_xor(ahi.z, m, 64);
            ahi.w += __shfl_xor(ahi.w, m, 64);
        }
        if (lane < 8) {
            uint4 sv = *(const uint4*)&hu[n * HIDDEN + cc8];
            float dn = dinv[n];
            ushort4 o0, o1;
            o0.x = f2bf(dn * (alo.x + __uint_as_float(sv.x << 16)));
            o0.y = f2bf(dn * (alo.y + __uint_as_float(sv.x & 0xffff0000u)));
            o0.z = f2bf(dn * (alo.z + __uint_as_float(sv.y << 16)));
            o0.w = f2bf(dn * (alo.w + __uint_as_float(sv.y & 0xffff0000u)));
            o1.x = f2bf(dn * (ahi.x + __uint_as_float(sv.z << 16)));
            o1.y = f2bf(dn * (ahi.y + __uint_as_float(sv.z & 0xffff0000u)));
            o1.z = f2bf(dn * (ahi.z + __uint_as_float(sv.w << 16)));
            o1.w = f2bf(dn * (ahi.w + __uint_as_float(sv.w & 0xffff0000u)));
            *(ushort4*)&sagg[row * AGG_LD + cc8] = o0;
            *(ushort4*)&sagg[row * AGG_LD + cc8 + 4] = o1;
        }
    }
    __syncthreads();

    // Phase B: MFMA on waves 0..3. Wave w computes all 16 nodes x channels [16w, 16w+16).
    if (w < 4) {
        int quad = lane >> 4;
        int col = lane & 15;
        int cch = w * 16 + col;
        bf16x8 a0 = *(const bf16x8*)&sagg[col * AGG_LD + quad * 8];
        bf16x8 a1 = *(const bf16x8*)&sagg[col * AGG_LD + 32 + quad * 8];
        bf16x8 b0 = *(const bf16x8*)&sW[cch * AGG_LD + quad * 8];
        bf16x8 b1 = *(const bf16x8*)&sW[cch * AGG_LD + 32 + quad * 8];
        f32x4 d = {0.f, 0.f, 0.f, 0.f};
        d = __builtin_amdgcn_mfma_f32_16x16x32_bf16(a0, b0, d, 0, 0, 0);
        d = __builtin_amdgcn_mfma_f32_16x16x32_bf16(a1, b1, d, 0, 0, 0);
        float bias = b[cch];
        float v[4];
#pragma unroll
        for (int r = 0; r < 4; r++) {
            float z = d[r] + bias;
            v[r] = z > 0.0f ? z : 0.0f;
        }

        // Phase C: pool from registers (batch sorted -> tile usually one graph)
        int glo = batch[n0];
        int ghi = batch[n0 + 15];
        if (glo == ghi) {
            float s4 = (v[0] + v[1]) + (v[2] + v[3]);
            s4 += __shfl_xor(s4, 16, 64);
            s4 += __shfl_xor(s4, 32, 64);
            if (quad == 0) atomicAdd(&sums[glo * HIDDEN + cch], s4);
            if (t == 0) atomicAdd(&cntg[glo], 16.0f);
        } else {
#pragma unroll
            for (int r = 0; r < 4; r++) {
                int g = batch[n0 + quad * 4 + r];
                if ((unsigned)g < N_GRAPHS) atomicAdd(&sums[g * HIDDEN + cch], v[r]);
            }
            if (w == 0 && col == 0) {
#pragma unroll
                for (int r = 0; r < 4; r++) {
                    int g = batch[n0 + quad * 4 + r];
                    if ((unsigned)g < N_GRAPHS) atomicAdd(&cntg[g], 1.0f);
                }
            }
        }
    }
}

// ---------------- head ----------------

__global__ void head_kernel(const float* __restrict__ sums, const float* __restrict__ cntg,
                            const float* __restrict__ Wc, const float* __restrict__ bc,
                            float* __restrict__ out) {
    int t = blockIdx.x * blockDim.x + threadIdx.x;
    if (t >= N_GRAPHS * OUT_CH) return;
    int g = t >> 1;
    int o = t & 1;
    float inv = 1.0f / fmaxf(cntg[g], 1.0f);
    float acc = bc[o];
#pragma unroll
    for (int k = 0; k < HIDDEN; k++) acc += sums[g * HIDDEN + k] * inv * Wc[k * OUT_CH + o];
    out[t] = acc;
}

// ---------------- launch ----------------

extern "C" void kernel_launch(void* const* d_in, const int* in_sizes, int n_in,
                              void* d_out, int out_size, void* d_ws, size_t ws_size,
                              hipStream_t stream) {
    const float* x  = (const float*)d_in[0];
    const int* ei   = (const int*)d_in[1];
    const int* bat  = (const int*)d_in[2];
    const float* W1 = (const float*)d_in[3];
    const float* b1 = (const float*)d_in[4];
    const float* W2 = (const float*)d_in[5];
    const float* b2 = (const float*)d_in[6];
    const float* Wc = (const float*)d_in[7];
    const float* bc = (const float*)d_in[8];
    float* out = (float*)d_out;

    const int* src = ei;
    const int* dst = ei + N_EDGES;

    char* ws = (char*)d_ws;
    size_t off = 0;
    auto carve = [&](size_t nbytes) {
        char* p = ws + off;
        off += (nbytes + 255) & ~(size_t)255;
        return p;
    };
    float* sums     = (float*)carve(N_GRAPHS * HIDDEN * sizeof(float));
    float* cntg     = (float*)carve(N_GRAPHS * sizeof(float));
    unsigned short* w2t = (unsigned short*)carve(W2T_ENT * sizeof(unsigned short));
    int*   csr      = (int*)carve((size_t)NB * BCAP * sizeof(int));
    int*   rowptr   = (int*)carve(N_NODES * sizeof(int));
    int*   cnt_node = (int*)carve(N_NODES * sizeof(int));
    int*   cur      = (int*)carve(N_NODES * sizeof(int));
    float* dinv     = (float*)carve(N_NODES * sizeof(float));
    unsigned short* xs = (unsigned short*)carve((size_t)N_NODES * IN_CH * sizeof(unsigned short));
    __hip_bfloat16* bufA = (__hip_bfloat16*)carve((size_t)N_NODES * HIDDEN * sizeof(__hip_bfloat16));
    (void)ws_size;

    const int node16Blk = (N_NODES + 15) / 16;   // 3125
    const int edgeBlk = (EQ4 + 255) / 256;       // 782

    init_kernel<<<64, 256, 0, stream>>>(cnt_node, sums, cntg, W2, w2t);
    degree_kernel<<<edgeBlk, 256, 0, stream>>>(dst, cnt_node);
    bucket_prefix_kernel<<<NB, 256, 0, stream>>>(cnt_node, rowptr, cur, dinv, x, xs);
    scatter_kernel<<<edgeBlk, 256, 0, stream>>>(src, dst, cur, csr);
    fused_l1_kernel<<<node16Blk, 512, 0, stream>>>(xs, csr, rowptr, cnt_node, dinv, W1, b1, bufA);
    fused_l2_kernel<<<node16Blk, 512, 0, stream>>>(bufA, csr, rowptr, cnt_node, dinv, w2t, b2,
                                                   bat, sums, cntg);
    head_kernel<<<1, 256, 0, stream>>>(sums, cntg, Wc, bc, out);
}